// Round 6
// baseline (162.669 us; speedup 1.0000x reference)
//
#include <hip/hip_runtime.h>

#define NEDGE  1600000
#define NPT    (NEDGE / 16)   // 100000 16-edge tiles
#define GRID   5000           // one wave-pair per block; oversubscribe CUs
#define NIT    (NPT / GRID)   // 20 — exact, no tail
#define NNODE  100000
#define NB_OFF 32768                       // ushort offset of bf16 node cache in ws
#define WS_BYTES (65536 + NNODE * 32 * 2)  // frags + bf16 nodes = 6,465,536

typedef float f32x4  __attribute__((ext_vector_type(4)));
typedef short short8 __attribute__((ext_vector_type(8)));

static __device__ __forceinline__ ushort f2bf(float f) {
  uint u = __builtin_bit_cast(uint, f);
  return (ushort)((u + 0x7FFFu + ((u >> 16) & 1u)) >> 16);   // RNE
}
static __device__ __forceinline__ uint cvt_pk(float lo, float hi) {
  uint r; asm("v_cvt_pk_bf16_f32 %0, %1, %2" : "=v"(r) : "v"(lo), "v"(hi)); return r;
}
static __device__ __forceinline__ float vexp2(float x) {
  float r; asm("v_exp_f32 %0, %1" : "=v"(r) : "v"(x)); return r;
}
static __device__ __forceinline__ float vrcp(float x) {
  float r; asm("v_rcp_f32 %0, %1" : "=v"(r) : "v"(x)); return r;
}
static __device__ __forceinline__ short8 pack8(float4 a, float4 b) {
  uint4 u;
  u.x = cvt_pk(a.x, a.y); u.y = cvt_pk(a.z, a.w);
  u.z = cvt_pk(b.x, b.y); u.w = cvt_pk(b.z, b.w);
  return __builtin_bit_cast(short8, u);
}

// Pre-pack W1 (scaled by -log2e, bias row at k=80, zeros to k=96, hid-permuted)
// and W2 into MFMA fragment layout. 20480 bf16 elements.
__global__ void prep_frags(const float* __restrict__ W1, const float* __restrict__ b1,
                           const float* __restrict__ W2, ushort* __restrict__ ws) {
  const int idx = blockIdx.x * 256 + threadIdx.x;
  if (idx >= 20480) return;
  const int frag = idx >> 9;
  const int lane = (idx >> 3) & 63;
  const int j    = idx & 7;
  const int g = lane >> 4, c = lane & 15;
  ushort v;
  if (frag < 30) {                    // W1^T A-frags: frag = wh*15 + mt*3 + kt
    const int wh = frag / 15, rem = frag % 15, mt = rem / 3, kt = rem % 3;
    const int k   = kt * 32 + g * 8 + j;
    const int hid = 32 * mt + 8 * (c >> 2) + 4 * wh + (c & 3);   // permutation P
    const float s = -1.44269504088896f;
    const float val = (k < 80) ? W1[k * 160 + hid] * s
                               : (k == 80 ? b1[hid] * s : 0.0f);
    v = f2bf(val);
  } else {                            // W2^T A-frags: frag-30 = wh*5 + kt
    const int f2 = frag - 30, wh = f2 / 5, kt = f2 % 5;
    const int k = kt * 32 + g * 8 + j;
    v = f2bf(W2[k * 32 + 16 * wh + c]);
  }
  ws[idx] = v;
}

// nodes f32 -> bf16 cache (row = 32 bf16 = 64B)
__global__ void prep_nodes(const float* __restrict__ nodes, ushort* __restrict__ nb) {
  const int idx = blockIdx.x * 256 + threadIdx.x;   // one per 8 floats
  if (idx >= NNODE * 4) return;
  const float4 a = ((const float4*)nodes)[idx * 2];
  const float4 b = ((const float4*)nodes)[idx * 2 + 1];
  *(short8*)(nb + (size_t)idx * 8) = pack8(a, b);
}

template <bool USE_WS>
__global__ __launch_bounds__(128) void edge_mlp(
    const float* __restrict__ nodes, const float* __restrict__ edges,
    const int* __restrict__ senders, const int* __restrict__ receivers,
    const float* __restrict__ W1, const float* __restrict__ b1,
    const float* __restrict__ W2, const float* __restrict__ b2,
    float* __restrict__ out, const ushort* __restrict__ ws)
{
  __shared__ uint2 X[2][2][5][64];   // [wave][dbuf][kt][lane] h-half exchange, 10 KB

  const int lane = threadIdx.x & 63;
  const int wh   = threadIdx.x >> 6;
  const int g    = lane >> 4;
  const int c    = lane & 15;
  const ushort* nb = USE_WS ? (ws + NB_OFF) : nullptr;

  // ---- weight fragments in registers ----
  short8 w1f[5][3];
  short8 w2f[5];
  if constexpr (USE_WS) {
#pragma unroll
    for (int mt = 0; mt < 5; ++mt)
#pragma unroll
      for (int kt = 0; kt < 3; ++kt)
        w1f[mt][kt] = *(const short8*)(ws + ((wh * 15 + mt * 3 + kt) * 64 + lane) * 8);
#pragma unroll
    for (int kt = 0; kt < 5; ++kt)
      w2f[kt] = *(const short8*)(ws + ((30 + wh * 5 + kt) * 64 + lane) * 8);
  } else {
    const float s = -1.44269504088896f;
    const int hidb = 8 * (c >> 2) + 4 * wh + (c & 3);
#pragma unroll
    for (int mt = 0; mt < 5; ++mt)
#pragma unroll
      for (int kt = 0; kt < 3; ++kt) {
        const int hid = 32 * mt + hidb;
        uint d[4];
#pragma unroll
        for (int dw = 0; dw < 4; ++dw) {
          const int k0 = kt * 32 + g * 8 + dw * 2, k1 = k0 + 1;
          const float f0 = (k0 < 80) ? W1[k0 * 160 + hid] * s : (k0 == 80 ? b1[hid] * s : 0.f);
          const float f1 = (k1 < 80) ? W1[k1 * 160 + hid] * s : (k1 == 80 ? b1[hid] * s : 0.f);
          d[dw] = (uint)f2bf(f0) | ((uint)f2bf(f1) << 16);
        }
        w1f[mt][kt] = __builtin_bit_cast(short8, make_uint4(d[0], d[1], d[2], d[3]));
      }
#pragma unroll
    for (int kt = 0; kt < 5; ++kt) {
      uint d[4];
#pragma unroll
      for (int dw = 0; dw < 4; ++dw) {
        const int k = kt * 32 + g * 8 + dw * 2;
        d[dw] = (uint)f2bf(W2[k * 32 + wh * 16 + c]) |
                ((uint)f2bf(W2[(k + 1) * 32 + wh * 16 + c]) << 16);
      }
      w2f[kt] = __builtin_bit_cast(short8, make_uint4(d[0], d[1], d[2], d[3]));
    }
  }
  const float4 b2v = *(const float4*)(b2 + wh * 16 + g * 4);
  const f32x4 b2c = (f32x4){b2v.x, b2v.y, b2v.z, b2v.w};   // persistent C for L2 chain
  const f32x4 z4  = (f32x4){0.f, 0.f, 0.f, 0.f};           // persistent C for L1 head
  const uint  cE0 = (g == 2) ? 0x3F80u : 0u;               // bf16(1.0) at k==80

  // ---- prologue: tile 0 gather + tile 1 indices ----
  int t = blockIdx.x;
  int e = t * 16 + c;
  short8 bfS_p, bfR_p;                 // USE_WS path: direct bf16 node frags
  float4 sn0, sn1, rn0, rn1;           // fallback path: f32 node rows
  float4 ee0, ee1;
  {
    const int si = senders[e], ri = receivers[e];
    if constexpr (USE_WS) {
      bfS_p = *(const short8*)(nb + (size_t)si * 32 + g * 8);
      bfR_p = *(const short8*)(nb + (size_t)ri * 32 + g * 8);
    } else {
      const float* sp = nodes + (size_t)si * 32 + g * 8;
      sn0 = *(const float4*)sp;  sn1 = *(const float4*)(sp + 4);
      const float* rp = nodes + (size_t)ri * 32 + g * 8;
      rn0 = *(const float4*)rp;  rn1 = *(const float4*)(rp + 4);
    }
    const float* ep = edges + (size_t)e * 16 + (g & 1) * 8;
    ee0 = *(const float4*)ep;  ee1 = *(const float4*)(ep + 4);
  }
  int e1 = (t + GRID) * 16 + c;
  int si1 = senders[e1], ri1 = receivers[e1];

  for (int i = 0; i < NIT; ++i) {
    const int buf = i & 1;

    // 1) edge feats -> bf16 frag (nodes need no pack on the USE_WS path)
    uint4 ue;
    ue.x = (g < 2) ? cvt_pk(ee0.x, ee0.y) : cE0;
    ue.y = (g < 2) ? cvt_pk(ee0.z, ee0.w) : 0u;
    ue.z = (g < 2) ? cvt_pk(ee1.x, ee1.y) : 0u;
    ue.w = (g < 2) ? cvt_pk(ee1.z, ee1.w) : 0u;
    const short8 bfE = __builtin_bit_cast(short8, ue);
    short8 bfS, bfR;
    if constexpr (USE_WS) { bfS = bfS_p;            bfR = bfR_p; }
    else                  { bfS = pack8(sn0, sn1);  bfR = pack8(rn0, rn1); }

    // 2) L1 swapped: acc[mt] = (W1^T)(mt) x feats^T ; head MFMA uses C=z4 (no zero-init)
    f32x4 acc[5];
#pragma unroll
    for (int mt = 0; mt < 5; ++mt)
      acc[mt] = __builtin_amdgcn_mfma_f32_16x16x32_bf16(w1f[mt][0], bfS, z4, 0, 0, 0);
#pragma unroll
    for (int mt = 0; mt < 5; ++mt)
      acc[mt] = __builtin_amdgcn_mfma_f32_16x16x32_bf16(w1f[mt][1], bfR, acc[mt], 0, 0, 0);
#pragma unroll
    for (int mt = 0; mt < 5; ++mt)
      acc[mt] = __builtin_amdgcn_mfma_f32_16x16x32_bf16(w1f[mt][2], bfE, acc[mt], 0, 0, 0);

    // 3) prefetch next tile (edges, nodes, then indices 2-ahead)
    {
      int tn = t + GRID; if (tn >= NPT) tn = t;
      const int en = tn * 16 + c;
      const float* epn = edges + (size_t)en * 16 + (g & 1) * 8;
      ee0 = *(const float4*)epn;  ee1 = *(const float4*)(epn + 4);
      if constexpr (USE_WS) {
        bfS_p = *(const short8*)(nb + (size_t)si1 * 32 + g * 8);
        bfR_p = *(const short8*)(nb + (size_t)ri1 * 32 + g * 8);
      } else {
        const float* spn = nodes + (size_t)si1 * 32 + g * 8;
        sn0 = *(const float4*)spn;  sn1 = *(const float4*)(spn + 4);
        const float* rpn = nodes + (size_t)ri1 * 32 + g * 8;
        rn0 = *(const float4*)rpn;  rn1 = *(const float4*)(rpn + 4);
      }
      int t2 = t + 2 * GRID; if (t2 >= NPT) t2 = tn;
      const int e2 = t2 * 16 + c;
      si1 = senders[e2];  ri1 = receivers[e2];
    }

    // 4) sigmoid in-register (scale folded into W1/b1): h = rcp(1+exp2(x))
    uint pkA[5], pkB[5];
#pragma unroll
    for (int mt = 0; mt < 5; ++mt) {
      const float h0 = vrcp(1.0f + vexp2(acc[mt][0]));
      const float h1 = vrcp(1.0f + vexp2(acc[mt][1]));
      const float h2 = vrcp(1.0f + vexp2(acc[mt][2]));
      const float h3 = vrcp(1.0f + vexp2(acc[mt][3]));
      pkA[mt] = cvt_pk(h0, h1);
      pkB[mt] = cvt_pk(h2, h3);
    }

    // 5) lane-aligned half exchange with partner wave
#pragma unroll
    for (int kt = 0; kt < 5; ++kt) X[wh][buf][kt][lane] = make_uint2(pkA[kt], pkB[kt]);
    asm volatile("s_waitcnt lgkmcnt(0)\n\ts_barrier" ::: "memory");
    uint2 q[5];
#pragma unroll
    for (int kt = 0; kt < 5; ++kt) q[kt] = X[wh ^ 1][buf][kt][lane];

    // 6) L2 swapped, single chained accumulator seeded with b2 (C-operand trick)
    f32x4 o;
    if (wh == 0) {
      o = __builtin_amdgcn_mfma_f32_16x16x32_bf16(w2f[0],
            __builtin_bit_cast(short8, make_uint4(pkA[0], pkB[0], q[0].x, q[0].y)), b2c, 0, 0, 0);
#pragma unroll
      for (int kt = 1; kt < 5; ++kt)
        o = __builtin_amdgcn_mfma_f32_16x16x32_bf16(w2f[kt],
              __builtin_bit_cast(short8, make_uint4(pkA[kt], pkB[kt], q[kt].x, q[kt].y)), o, 0, 0, 0);
    } else {
      o = __builtin_amdgcn_mfma_f32_16x16x32_bf16(w2f[0],
            __builtin_bit_cast(short8, make_uint4(q[0].x, q[0].y, pkA[0], pkB[0])), b2c, 0, 0, 0);
#pragma unroll
      for (int kt = 1; kt < 5; ++kt)
        o = __builtin_amdgcn_mfma_f32_16x16x32_bf16(w2f[kt],
              __builtin_bit_cast(short8, make_uint4(q[kt].x, q[kt].y, pkA[kt], pkB[kt])), o, 0, 0, 0);
    }

    // 7) coalesced store
    float4 st; st.x = o[0]; st.y = o[1]; st.z = o[2]; st.w = o[3];
    *(float4*)(out + (size_t)e * 32 + wh * 16 + g * 4) = st;

    t += GRID;
    e = t * 16 + c;
  }
}

extern "C" void kernel_launch(void* const* d_in, const int* in_sizes, int n_in,
                              void* d_out, int out_size, void* d_ws, size_t ws_size,
                              hipStream_t stream) {
  const float* nodes     = (const float*)d_in[0];
  const float* edges     = (const float*)d_in[1];
  const int*   senders   = (const int*)d_in[2];
  const int*   receivers = (const int*)d_in[3];
  const float* W1        = (const float*)d_in[4];
  const float* b1        = (const float*)d_in[5];
  const float* W2        = (const float*)d_in[6];
  const float* b2        = (const float*)d_in[7];
  float* out = (float*)d_out;

  if (ws_size >= (size_t)WS_BYTES) {
    ushort* ws = (ushort*)d_ws;
    prep_frags<<<80, 256, 0, stream>>>(W1, b1, W2, ws);
    prep_nodes<<<(NNODE * 4 + 255) / 256, 256, 0, stream>>>(nodes, ws + NB_OFF);
    edge_mlp<true><<<GRID, 128, 0, stream>>>(nodes, edges, senders, receivers,
                                             W1, b1, W2, b2, out, ws);
  } else {
    edge_mlp<false><<<GRID, 128, 0, stream>>>(nodes, edges, senders, receivers,
                                              W1, b1, W2, b2, out, nullptr);
  }
}